// Round 5
// baseline (62.152 us; speedup 1.0000x reference)
//
#include <hip/hip_runtime.h>
#include <hip/hip_fp16.h>

// Problem constants (reference: B,N,D,H,C = 4,512,128,128,3)
#define B_ 4
#define N_ 512
#define D_ 128
#define H_ 128
#define C_ 3

#define NEG_LOG2E   (-1.4426950408889634f)
#define NEG_HALF_LN2 (-0.34657359027997264f)   // -0.5 * ln(2)
#define ROWP 136   // f16 LDS row stride: 128 + 8 pad -> row stride 68 banks == 4 mod 32

typedef _Float16 half8  __attribute__((ext_vector_type(8)));
typedef _Float16 half4v __attribute__((ext_vector_type(4)));

__device__ __forceinline__ float exp2_fast(float x) {
    return __builtin_amdgcn_exp2f(x);   // raw v_exp_f32 (2^x)
}

// Projections stored PRE-SCALED by -log2e, in f16:
//   At[row][h] = f16(-log2e * (dot(h[row], W1[h][0:128]) + b1[h]))
//   Bt[row][h] = f16(-log2e *  dot(h[row], W1[h][128:256]))
// BM=32, BN=64, BK=64, 256 threads, 2x4 thread tile -> 256 blocks (1/CU).
__global__ __launch_bounds__(256) void proj_gemm(
    const float* __restrict__ hd, const float* __restrict__ W1,
    const float* __restrict__ b1, _Float16* __restrict__ At, _Float16* __restrict__ Bt)
{
    __shared__ float hsT[64][36];   // [k][m]
    __shared__ float wt [64][68];   // [k][o]
    const int m0      = blockIdx.x * 32;
    const int by      = blockIdx.y;        // 0..3
    const int halfSel = by >> 1;           // 0 -> At, 1 -> Bt
    const int wrow0   = (by & 1) * 64;     // W1 row base (== output h-col base)

    const int t  = threadIdx.x;
    const int r  = t >> 4, c4 = t & 15;    // staging decomposition
    const int tx = t & 15, ty = t >> 4;    // compute: cols 4tx.., rows 2ty..

    float acc[2][4] = {};

    for (int kc = 0; kc < 2; ++kc) {
        if (kc) __syncthreads();
        #pragma unroll
        for (int i = 0; i < 2; ++i) {      // 32 m-rows
            const int m = r + 16 * i;
            float4 v = *(const float4*)&hd[(m0 + m) * D_ + kc * 64 + 4 * c4];
            hsT[4 * c4 + 0][m] = v.x; hsT[4 * c4 + 1][m] = v.y;
            hsT[4 * c4 + 2][m] = v.z; hsT[4 * c4 + 3][m] = v.w;
        }
        #pragma unroll
        for (int i = 0; i < 4; ++i) {      // 64 o-rows
            const int o = r + 16 * i;
            float4 v = *(const float4*)&W1[(wrow0 + o) * (2 * D_) + halfSel * D_ + kc * 64 + 4 * c4];
            wt[4 * c4 + 0][o] = v.x; wt[4 * c4 + 1][o] = v.y;
            wt[4 * c4 + 2][o] = v.z; wt[4 * c4 + 3][o] = v.w;
        }
        __syncthreads();
        #pragma unroll 8
        for (int k = 0; k < 64; ++k) {
            float2 a  = *(const float2*)&hsT[k][2 * ty];
            float4 bv = *(const float4*)&wt [k][4 * tx];
            acc[0][0] = fmaf(a.x, bv.x, acc[0][0]); acc[0][1] = fmaf(a.x, bv.y, acc[0][1]);
            acc[0][2] = fmaf(a.x, bv.z, acc[0][2]); acc[0][3] = fmaf(a.x, bv.w, acc[0][3]);
            acc[1][0] = fmaf(a.y, bv.x, acc[1][0]); acc[1][1] = fmaf(a.y, bv.y, acc[1][1]);
            acc[1][2] = fmaf(a.y, bv.z, acc[1][2]); acc[1][3] = fmaf(a.y, bv.w, acc[1][3]);
        }
    }

    _Float16* dst = halfSel ? Bt : At;
    const int ocol = wrow0 + 4 * tx;
    float4 bias = make_float4(0.f, 0.f, 0.f, 0.f);
    if (!halfSel) bias = *(const float4*)&b1[ocol];
    #pragma unroll
    for (int i = 0; i < 2; ++i) {
        half4v o;
        o[0] = (_Float16)((acc[i][0] + bias.x) * NEG_LOG2E);
        o[1] = (_Float16)((acc[i][1] + bias.y) * NEG_LOG2E);
        o[2] = (_Float16)((acc[i][2] + bias.z) * NEG_LOG2E);
        o[3] = (_Float16)((acc[i][3] + bias.w) * NEG_LOG2E);
        *(half4v*)&dst[(m0 + 2 * ty + i) * H_ + ocol] = o;   // 8B store
    }
}

// One block per (batch, upper-tri 32x32 tile pair). 16x16 threads, each owns a
// 2x2 pair tile: i in {ti, ti+16} of I-tile, j in {tj, tj+16} of J-tile.
// Per (pair,h):  y1 = At_i+Bt_j, y2 = At_j+Bt_i (pre-scaled by -log2e), then
//   s = (y1*d2 + y2*d1) * rcp(d1*d2),  d = 1 + 2^y   (1 shared v_rcp, 2 v_exp)
//   acc_c += s * W2[c][h];   out_c = -ln2/2 * acc_c + b2_c   (both orders written)
__global__ __launch_bounds__(256, 4) void pair_kernel(
    const _Float16* __restrict__ At, const _Float16* __restrict__ Bt,
    const float* __restrict__ W2, const float* __restrict__ b2,
    float* __restrict__ out)
{
    __shared__ __align__(16) _Float16 AI[32 * ROWP], AJ[32 * ROWP];
    __shared__ __align__(16) _Float16 BI[32 * ROWP], BJ[32 * ROWP];
    const int T = N_ / 32;  // 16 tiles per dim
    int tp = blockIdx.x;
    const int b = blockIdx.y;
    int I = 0;
    while (tp >= T - I) { tp -= T - I; ++I; }   // uniform scalar decode
    const int J = I + tp;

    const int tid = threadIdx.x;
    const half8* sAI = (const half8*)(At + (b * N_ + I * 32) * H_);
    const half8* sAJ = (const half8*)(At + (b * N_ + J * 32) * H_);
    const half8* sBI = (const half8*)(Bt + (b * N_ + I * 32) * H_);
    const half8* sBJ = (const half8*)(Bt + (b * N_ + J * 32) * H_);
    #pragma unroll
    for (int k = tid; k < 512; k += 256) {      // 32 rows x 16 half8 per tile
        const int r = k >> 4, c = (k & 15) * 8;
        *(half8*)&AI[r * ROWP + c] = sAI[k];
        *(half8*)&AJ[r * ROWP + c] = sAJ[k];
        *(half8*)&BI[r * ROWP + c] = sBI[k];
        *(half8*)&BJ[r * ROWP + c] = sBJ[k];
    }
    __syncthreads();

    const int ti = tid >> 4, tj = tid & 15;
    float acc[4][3] = {};

    #pragma unroll 2
    for (int h8 = 0; h8 < H_ / 8; ++h8) {
        const int hb = h8 * 8;
        half8 vAI0 = *(const half8*)&AI[ ti       * ROWP + hb];
        half8 vAI1 = *(const half8*)&AI[(ti + 16) * ROWP + hb];
        half8 vBI0 = *(const half8*)&BI[ ti       * ROWP + hb];
        half8 vBI1 = *(const half8*)&BI[(ti + 16) * ROWP + hb];
        half8 vAJ0 = *(const half8*)&AJ[ tj       * ROWP + hb];
        half8 vAJ1 = *(const half8*)&AJ[(tj + 16) * ROWP + hb];
        half8 vBJ0 = *(const half8*)&BJ[ tj       * ROWP + hb];
        half8 vBJ1 = *(const half8*)&BJ[(tj + 16) * ROWP + hb];
        // W2 rows: uniform addresses -> scalar loads
        float4 w0a = *(const float4*)&W2[hb],          w0b = *(const float4*)&W2[hb + 4];
        float4 w1a = *(const float4*)&W2[H_ + hb],     w1b = *(const float4*)&W2[H_ + hb + 4];
        float4 w2a = *(const float4*)&W2[2 * H_ + hb], w2b = *(const float4*)&W2[2 * H_ + hb + 4];
        const float w0[8] = {w0a.x, w0a.y, w0a.z, w0a.w, w0b.x, w0b.y, w0b.z, w0b.w};
        const float w1[8] = {w1a.x, w1a.y, w1a.z, w1a.w, w1b.x, w1b.y, w1b.z, w1b.w};
        const float w2[8] = {w2a.x, w2a.y, w2a.z, w2a.w, w2b.x, w2b.y, w2b.z, w2b.w};

        #pragma unroll
        for (int e = 0; e < 8; ++e) {
            const float ai0 = (float)vAI0[e], ai1 = (float)vAI1[e];
            const float aj0 = (float)vAJ0[e], aj1 = (float)vAJ1[e];
            const float bi0 = (float)vBI0[e], bi1 = (float)vBI1[e];
            const float bj0 = (float)vBJ0[e], bj1 = (float)vBJ1[e];

            #define SILU_ACC(p, AIv, BJv, AJv, BIv)                               \
            {                                                                     \
                const float y1 = (AIv) + (BJv);                                   \
                const float y2 = (AJv) + (BIv);                                   \
                const float d1 = 1.0f + exp2_fast(y1);                            \
                const float d2 = 1.0f + exp2_fast(y2);                            \
                const float rr = __builtin_amdgcn_rcpf(d1 * d2);                  \
                const float s  = fmaf(y2, d1, y1 * d2) * rr;                      \
                acc[p][0] = fmaf(s, w0[e], acc[p][0]);                            \
                acc[p][1] = fmaf(s, w1[e], acc[p][1]);                            \
                acc[p][2] = fmaf(s, w2[e], acc[p][2]);                            \
            }
            SILU_ACC(0, ai0, bj0, aj0, bi0)
            SILU_ACC(1, ai0, bj1, aj1, bi0)
            SILU_ACC(2, ai1, bj0, aj0, bi1)
            SILU_ACC(3, ai1, bj1, aj1, bi1)
            #undef SILU_ACC
        }
    }

    const float b20 = b2[0], b21 = b2[1], b22 = b2[2];
    #pragma unroll
    for (int p = 0; p < 4; ++p) {
        const int i = I * 32 + ti + ((p >> 1) ? 16 : 0);
        const int j = J * 32 + tj + ((p & 1) ? 16 : 0);
        const float o0 = fmaf(NEG_HALF_LN2, acc[p][0], b20);
        const float o1 = fmaf(NEG_HALF_LN2, acc[p][1], b21);
        const float o2 = fmaf(NEG_HALF_LN2, acc[p][2], b22);
        float* p1 = out + ((size_t)(b * N_ + i) * N_ + j) * C_;
        float* p2 = out + ((size_t)(b * N_ + j) * N_ + i) * C_;
        p1[0] = o0; p1[1] = o1; p1[2] = o2;
        p2[0] = o0; p2[1] = o1; p2[2] = o2;   // diagonal tiles: identical duplicate, benign
    }
}

extern "C" void kernel_launch(void* const* d_in, const int* in_sizes, int n_in,
                              void* d_out, int out_size, void* d_ws, size_t ws_size,
                              hipStream_t stream) {
    const float* hd = (const float*)d_in[0];
    const float* W1 = (const float*)d_in[1];
    const float* b1 = (const float*)d_in[2];
    const float* W2 = (const float*)d_in[3];
    const float* b2 = (const float*)d_in[4];
    float* out = (float*)d_out;

    _Float16* At = (_Float16*)d_ws;          // [B*N][H] f16 = 512 KiB (scaled by -log2e)
    _Float16* Bt = At + B_ * N_ * H_;        // [B*N][H] f16 = 512 KiB

    proj_gemm<<<dim3((B_ * N_) / 32, 4), dim3(256), 0, stream>>>(hd, W1, b1, At, Bt);

    const int T = N_ / 32;                   // 16 -> 136 upper-tri tile pairs
    pair_kernel<<<dim3(T * (T + 1) / 2, B_), dim3(256), 0, stream>>>(At, Bt, W2, b2, out);
}

// Round 6
// 48.077 us; speedup vs baseline: 1.2927x; 1.2927x over previous
//
#include <hip/hip_runtime.h>
#include <hip/hip_fp16.h>

// Problem constants (reference: B,N,D,H,C = 4,512,128,128,3)
#define B_ 4
#define N_ 512
#define D_ 128
#define H_ 128
#define C_ 3

#define NEG_LOG2E   (-1.4426950408889634f)
#define NEG_HALF_LN2 (-0.34657359027997264f)   // -0.5 * ln(2)
#define ROWP 136   // f16 LDS row stride: 272 B -> 68 banks == 4 mod 32 per row

typedef _Float16 half8  __attribute__((ext_vector_type(8)));
typedef _Float16 half4v __attribute__((ext_vector_type(4)));

__device__ __forceinline__ float exp2_fast(float x) {
    return __builtin_amdgcn_exp2f(x);   // raw v_exp_f32 (2^x)
}

// Projections stored PRE-SCALED by -log2e, in f16:
//   At[row][h] = f16(-log2e * (dot(h[row], W1[h][0:128]) + b1[h]))
//   Bt[row][h] = f16(-log2e *  dot(h[row], W1[h][128:256]))
// BM=32, BN=64, BK=64, 256 threads, 2x4 thread tile -> 256 blocks.
__global__ __launch_bounds__(256) void proj_gemm(
    const float* __restrict__ hd, const float* __restrict__ W1,
    const float* __restrict__ b1, _Float16* __restrict__ At, _Float16* __restrict__ Bt)
{
    __shared__ float hsT[64][36];   // [k][m]
    __shared__ float wt [64][68];   // [k][o]
    const int m0      = blockIdx.x * 32;
    const int by      = blockIdx.y;        // 0..3
    const int halfSel = by >> 1;           // 0 -> At, 1 -> Bt
    const int wrow0   = (by & 1) * 64;     // W1 row base (== output h-col base)

    const int t  = threadIdx.x;
    const int r  = t >> 4, c4 = t & 15;    // staging decomposition
    const int tx = t & 15, ty = t >> 4;    // compute: cols 4tx.., rows 2ty..

    float acc[2][4] = {};

    for (int kc = 0; kc < 2; ++kc) {
        if (kc) __syncthreads();
        #pragma unroll
        for (int i = 0; i < 2; ++i) {      // 32 m-rows
            const int m = r + 16 * i;
            float4 v = *(const float4*)&hd[(m0 + m) * D_ + kc * 64 + 4 * c4];
            hsT[4 * c4 + 0][m] = v.x; hsT[4 * c4 + 1][m] = v.y;
            hsT[4 * c4 + 2][m] = v.z; hsT[4 * c4 + 3][m] = v.w;
        }
        #pragma unroll
        for (int i = 0; i < 4; ++i) {      // 64 o-rows
            const int o = r + 16 * i;
            float4 v = *(const float4*)&W1[(wrow0 + o) * (2 * D_) + halfSel * D_ + kc * 64 + 4 * c4];
            wt[4 * c4 + 0][o] = v.x; wt[4 * c4 + 1][o] = v.y;
            wt[4 * c4 + 2][o] = v.z; wt[4 * c4 + 3][o] = v.w;
        }
        __syncthreads();
        #pragma unroll 8
        for (int k = 0; k < 64; ++k) {
            float2 a  = *(const float2*)&hsT[k][2 * ty];
            float4 bv = *(const float4*)&wt [k][4 * tx];
            acc[0][0] = fmaf(a.x, bv.x, acc[0][0]); acc[0][1] = fmaf(a.x, bv.y, acc[0][1]);
            acc[0][2] = fmaf(a.x, bv.z, acc[0][2]); acc[0][3] = fmaf(a.x, bv.w, acc[0][3]);
            acc[1][0] = fmaf(a.y, bv.x, acc[1][0]); acc[1][1] = fmaf(a.y, bv.y, acc[1][1]);
            acc[1][2] = fmaf(a.y, bv.z, acc[1][2]); acc[1][3] = fmaf(a.y, bv.w, acc[1][3]);
        }
    }

    _Float16* dst = halfSel ? Bt : At;
    const int ocol = wrow0 + 4 * tx;
    float4 bias = make_float4(0.f, 0.f, 0.f, 0.f);
    if (!halfSel) bias = *(const float4*)&b1[ocol];
    #pragma unroll
    for (int i = 0; i < 2; ++i) {
        half4v o;
        o[0] = (_Float16)((acc[i][0] + bias.x) * NEG_LOG2E);
        o[1] = (_Float16)((acc[i][1] + bias.y) * NEG_LOG2E);
        o[2] = (_Float16)((acc[i][2] + bias.z) * NEG_LOG2E);
        o[3] = (_Float16)((acc[i][3] + bias.w) * NEG_LOG2E);
        *(half4v*)&dst[(m0 + 2 * ty + i) * H_ + ocol] = o;   // 8B store
    }
}

// One block per (batch, upper-tri 16x16 tile pair); thread (ti,tj) owns pair
// (i = I*16+ti, j = J*16+tj). Per (pair,h), with y pre-scaled by -log2e:
//   y1 = At_i+Bt_j, y2 = At_j+Bt_i              (f16 add + cvt each)
//   d  = 1 + 2^y                                (2 v_exp_f32)
//   s  = (y1*d2 + y2*d1) * rcp(d1*d2)           (shared v_rcp)
//   acc_c += s * W2[c][h]
// epilogue: out_c = -ln2/2 * acc_c + b2_c, written to (i,j) and (j,i).
__global__ __launch_bounds__(256, 8) void pair_kernel(
    const _Float16* __restrict__ At, const _Float16* __restrict__ Bt,
    const float* __restrict__ W2, const float* __restrict__ b2,
    float* __restrict__ out)
{
    __shared__ __align__(16) _Float16 AI[16 * ROWP], AJ[16 * ROWP];
    __shared__ __align__(16) _Float16 BI[16 * ROWP], BJ[16 * ROWP];   // 4 x 4352 B = 17408 B
    const int T = N_ / 16;  // 32 tiles per dim
    int tp = blockIdx.x;
    const int b = blockIdx.y;
    int I = 0;
    while (tp >= T - I) { tp -= T - I; ++I; }   // uniform scalar decode
    const int J = I + tp;

    const int tid = threadIdx.x;
    {   // 16 rows x 16 half8 per tile == 256 threads exactly
        const int r = tid >> 4, c = (tid & 15) * 8;
        const half8* sAI = (const half8*)(At + (b * N_ + I * 16) * H_);
        const half8* sAJ = (const half8*)(At + (b * N_ + J * 16) * H_);
        const half8* sBI = (const half8*)(Bt + (b * N_ + I * 16) * H_);
        const half8* sBJ = (const half8*)(Bt + (b * N_ + J * 16) * H_);
        *(half8*)&AI[r * ROWP + c] = sAI[tid];
        *(half8*)&AJ[r * ROWP + c] = sAJ[tid];
        *(half8*)&BI[r * ROWP + c] = sBI[tid];
        *(half8*)&BJ[r * ROWP + c] = sBJ[tid];
    }
    __syncthreads();

    const int ti = tid >> 4, tj = tid & 15;
    float acc0 = 0.f, acc1 = 0.f, acc2 = 0.f;

    #pragma unroll 4
    for (int h8 = 0; h8 < H_ / 8; ++h8) {
        const int hb = h8 * 8;
        half8 ai8 = *(const half8*)&AI[ti * ROWP + hb];   // 4 distinct rows -> conflict-free
        half8 bj8 = *(const half8*)&BJ[tj * ROWP + hb];   // 16 rows, 2-way -> free
        half8 aj8 = *(const half8*)&AJ[tj * ROWP + hb];
        half8 bi8 = *(const half8*)&BI[ti * ROWP + hb];
        // W2 rows: uniform addresses -> scalar loads
        float4 w0a = *(const float4*)&W2[hb],          w0b = *(const float4*)&W2[hb + 4];
        float4 w1a = *(const float4*)&W2[H_ + hb],     w1b = *(const float4*)&W2[H_ + hb + 4];
        float4 w2a = *(const float4*)&W2[2 * H_ + hb], w2b = *(const float4*)&W2[2 * H_ + hb + 4];
        const float w0[8] = {w0a.x, w0a.y, w0a.z, w0a.w, w0b.x, w0b.y, w0b.z, w0b.w};
        const float w1[8] = {w1a.x, w1a.y, w1a.z, w1a.w, w1b.x, w1b.y, w1b.z, w1b.w};
        const float w2[8] = {w2a.x, w2a.y, w2a.z, w2a.w, w2b.x, w2b.y, w2b.z, w2b.w};

        #pragma unroll
        for (int e = 0; e < 8; ++e) {
            const float y1 = (float)(ai8[e] + bj8[e]);    // v_add_f16 + v_cvt_f32_f16
            const float y2 = (float)(aj8[e] + bi8[e]);
            const float d1 = 1.0f + exp2_fast(y1);
            const float d2 = 1.0f + exp2_fast(y2);
            const float rr = __builtin_amdgcn_rcpf(d1 * d2);
            const float s  = fmaf(y2, d1, y1 * d2) * rr;
            acc0 = fmaf(s, w0[e], acc0);
            acc1 = fmaf(s, w1[e], acc1);
            acc2 = fmaf(s, w2[e], acc2);
        }
    }

    const float o0 = fmaf(NEG_HALF_LN2, acc0, b2[0]);
    const float o1 = fmaf(NEG_HALF_LN2, acc1, b2[1]);
    const float o2 = fmaf(NEG_HALF_LN2, acc2, b2[2]);
    const int i = I * 16 + ti, j = J * 16 + tj;
    float* p1 = out + ((size_t)(b * N_ + i) * N_ + j) * C_;
    float* p2 = out + ((size_t)(b * N_ + j) * N_ + i) * C_;
    p1[0] = o0; p1[1] = o1; p1[2] = o2;
    p2[0] = o0; p2[1] = o1; p2[2] = o2;   // diagonal tiles: identical duplicate, benign
}

extern "C" void kernel_launch(void* const* d_in, const int* in_sizes, int n_in,
                              void* d_out, int out_size, void* d_ws, size_t ws_size,
                              hipStream_t stream) {
    const float* hd = (const float*)d_in[0];
    const float* W1 = (const float*)d_in[1];
    const float* b1 = (const float*)d_in[2];
    const float* W2 = (const float*)d_in[3];
    const float* b2 = (const float*)d_in[4];
    float* out = (float*)d_out;

    _Float16* At = (_Float16*)d_ws;          // [B*N][H] f16 = 512 KiB (scaled by -log2e)
    _Float16* Bt = At + B_ * N_ * H_;        // [B*N][H] f16 = 512 KiB

    proj_gemm<<<dim3((B_ * N_) / 32, 4), dim3(256), 0, stream>>>(hd, W1, b1, At, Bt);

    const int T = N_ / 16;                   // 32 -> 528 upper-tri tile pairs
    pair_kernel<<<dim3(T * (T + 1) / 2, B_), dim3(256), 0, stream>>>(At, Bt, W2, b2, out);
}

// Round 7
// 43.234 us; speedup vs baseline: 1.4376x; 1.1120x over previous
//
#include <hip/hip_runtime.h>
#include <hip/hip_fp16.h>

// Problem constants (reference: B,N,D,H,C = 4,512,128,128,3)
#define B_ 4
#define N_ 512
#define D_ 128
#define H_ 128
#define C_ 3

#define NEG_LOG2E   (-1.4426950408889634f)
#define NEG_HALF_LN2 (-0.34657359027997264f)   // -0.5 * ln(2)
#define ROWP 136   // f16 LDS row stride: 272 B -> 68 banks == 4 mod 32 per row

typedef _Float16 half8  __attribute__((ext_vector_type(8)));
typedef _Float16 half4v __attribute__((ext_vector_type(4)));

__device__ __forceinline__ float exp2_fast(float x) {
    return __builtin_amdgcn_exp2f(x);   // raw v_exp_f32 (2^x)
}

// Projections stored PRE-SCALED by -log2e, in f16:
//   At[row][h] = f16(-log2e * (dot(h[row], W1[h][0:128]) + b1[h]))
//   Bt[row][h] = f16(-log2e *  dot(h[row], W1[h][128:256]))
// BM=32, BN=64, BK=64, 256 threads, 2x4 thread tile -> 256 blocks.
__global__ __launch_bounds__(256) void proj_gemm(
    const float* __restrict__ hd, const float* __restrict__ W1,
    const float* __restrict__ b1, _Float16* __restrict__ At, _Float16* __restrict__ Bt)
{
    __shared__ float hsT[64][36];   // [k][m]
    __shared__ float wt [64][68];   // [k][o]
    const int m0      = blockIdx.x * 32;
    const int by      = blockIdx.y;        // 0..3
    const int halfSel = by >> 1;           // 0 -> At, 1 -> Bt
    const int wrow0   = (by & 1) * 64;     // W1 row base (== output h-col base)

    const int t  = threadIdx.x;
    const int r  = t >> 4, c4 = t & 15;    // staging decomposition
    const int tx = t & 15, ty = t >> 4;    // compute: cols 4tx.., rows 2ty..

    float acc[2][4] = {};

    for (int kc = 0; kc < 2; ++kc) {
        if (kc) __syncthreads();
        #pragma unroll
        for (int i = 0; i < 2; ++i) {      // 32 m-rows
            const int m = r + 16 * i;
            float4 v = *(const float4*)&hd[(m0 + m) * D_ + kc * 64 + 4 * c4];
            hsT[4 * c4 + 0][m] = v.x; hsT[4 * c4 + 1][m] = v.y;
            hsT[4 * c4 + 2][m] = v.z; hsT[4 * c4 + 3][m] = v.w;
        }
        #pragma unroll
        for (int i = 0; i < 4; ++i) {      // 64 o-rows
            const int o = r + 16 * i;
            float4 v = *(const float4*)&W1[(wrow0 + o) * (2 * D_) + halfSel * D_ + kc * 64 + 4 * c4];
            wt[4 * c4 + 0][o] = v.x; wt[4 * c4 + 1][o] = v.y;
            wt[4 * c4 + 2][o] = v.z; wt[4 * c4 + 3][o] = v.w;
        }
        __syncthreads();
        #pragma unroll 8
        for (int k = 0; k < 64; ++k) {
            float2 a  = *(const float2*)&hsT[k][2 * ty];
            float4 bv = *(const float4*)&wt [k][4 * tx];
            acc[0][0] = fmaf(a.x, bv.x, acc[0][0]); acc[0][1] = fmaf(a.x, bv.y, acc[0][1]);
            acc[0][2] = fmaf(a.x, bv.z, acc[0][2]); acc[0][3] = fmaf(a.x, bv.w, acc[0][3]);
            acc[1][0] = fmaf(a.y, bv.x, acc[1][0]); acc[1][1] = fmaf(a.y, bv.y, acc[1][1]);
            acc[1][2] = fmaf(a.y, bv.z, acc[1][2]); acc[1][3] = fmaf(a.y, bv.w, acc[1][3]);
        }
    }

    _Float16* dst = halfSel ? Bt : At;
    const int ocol = wrow0 + 4 * tx;
    float4 bias = make_float4(0.f, 0.f, 0.f, 0.f);
    if (!halfSel) bias = *(const float4*)&b1[ocol];
    #pragma unroll
    for (int i = 0; i < 2; ++i) {
        half4v o;
        o[0] = (_Float16)((acc[i][0] + bias.x) * NEG_LOG2E);
        o[1] = (_Float16)((acc[i][1] + bias.y) * NEG_LOG2E);
        o[2] = (_Float16)((acc[i][2] + bias.z) * NEG_LOG2E);
        o[3] = (_Float16)((acc[i][3] + bias.w) * NEG_LOG2E);
        *(half4v*)&dst[(m0 + 2 * ty + i) * H_ + ocol] = o;   // 8B store
    }
}

// One block per (batch, upper-tri 16x16 tile pair); thread (ti,tj) owns pair
// (i = I*16+ti, j = J*16+tj). Inner loop is phase-batched over 8 h-elements so
// the compiler can pipeline 8 independent silu chains (needs VGPR headroom:
// launch_bounds(256,4); occupancy is LDS-capped at ~3 blocks/CU anyway).
__global__ __launch_bounds__(256, 4) void pair_kernel(
    const _Float16* __restrict__ At, const _Float16* __restrict__ Bt,
    const float* __restrict__ W2, const float* __restrict__ b2,
    float* __restrict__ out)
{
    __shared__ __align__(16) _Float16 AI[16 * ROWP], AJ[16 * ROWP];
    __shared__ __align__(16) _Float16 BI[16 * ROWP], BJ[16 * ROWP];   // 4 x 4352 B = 17408 B
    const int T = N_ / 16;  // 32 tiles per dim
    int tp = blockIdx.x;
    const int b = blockIdx.y;
    int I = 0;
    while (tp >= T - I) { tp -= T - I; ++I; }   // uniform scalar decode
    const int J = I + tp;

    const int tid = threadIdx.x;
    {   // 16 rows x 16 half8 per tile == 256 threads exactly
        const int r = tid >> 4, c = (tid & 15) * 8;
        const half8* sAI = (const half8*)(At + (b * N_ + I * 16) * H_);
        const half8* sAJ = (const half8*)(At + (b * N_ + J * 16) * H_);
        const half8* sBI = (const half8*)(Bt + (b * N_ + I * 16) * H_);
        const half8* sBJ = (const half8*)(Bt + (b * N_ + J * 16) * H_);
        *(half8*)&AI[r * ROWP + c] = sAI[tid];
        *(half8*)&AJ[r * ROWP + c] = sAJ[tid];
        *(half8*)&BI[r * ROWP + c] = sBI[tid];
        *(half8*)&BJ[r * ROWP + c] = sBJ[tid];
    }
    __syncthreads();

    const int ti = tid >> 4, tj = tid & 15;
    // split accumulators by e-parity to halve fma dependency-chain depth
    float acc0a = 0.f, acc1a = 0.f, acc2a = 0.f;
    float acc0b = 0.f, acc1b = 0.f, acc2b = 0.f;

    #pragma unroll 4
    for (int h8 = 0; h8 < H_ / 8; ++h8) {
        const int hb = h8 * 8;
        half8 ai8 = *(const half8*)&AI[ti * ROWP + hb];
        half8 bj8 = *(const half8*)&BJ[tj * ROWP + hb];
        half8 aj8 = *(const half8*)&AJ[tj * ROWP + hb];
        half8 bi8 = *(const half8*)&BI[ti * ROWP + hb];
        // phase 1: packed f16 adds (v_pk_add_f16), then widen
        half8 y1h = ai8 + bj8;
        half8 y2h = aj8 + bi8;
        float y1[8], y2[8], d1[8], d2[8], s[8];
        #pragma unroll
        for (int e = 0; e < 8; ++e) { y1[e] = (float)y1h[e]; y2[e] = (float)y2h[e]; }
        // phase 2: 16 exps batched back-to-back (trans pipe saturated, latency overlapped)
        #pragma unroll
        for (int e = 0; e < 8; ++e) { d1[e] = 1.0f + exp2_fast(y1[e]); }
        #pragma unroll
        for (int e = 0; e < 8; ++e) { d2[e] = 1.0f + exp2_fast(y2[e]); }
        // phase 3: shared rcp + rational combine
        #pragma unroll
        for (int e = 0; e < 8; ++e) {
            const float rr = __builtin_amdgcn_rcpf(d1[e] * d2[e]);
            s[e] = fmaf(y2[e], d1[e], y1[e] * d2[e]) * rr;
        }
        // phase 4: W2 contraction (uniform scalar W2 loads)
        float4 w0a = *(const float4*)&W2[hb],          w0b = *(const float4*)&W2[hb + 4];
        float4 w1a = *(const float4*)&W2[H_ + hb],     w1b = *(const float4*)&W2[H_ + hb + 4];
        float4 w2a = *(const float4*)&W2[2 * H_ + hb], w2b = *(const float4*)&W2[2 * H_ + hb + 4];
        const float w0[8] = {w0a.x, w0a.y, w0a.z, w0a.w, w0b.x, w0b.y, w0b.z, w0b.w};
        const float w1[8] = {w1a.x, w1a.y, w1a.z, w1a.w, w1b.x, w1b.y, w1b.z, w1b.w};
        const float w2[8] = {w2a.x, w2a.y, w2a.z, w2a.w, w2b.x, w2b.y, w2b.z, w2b.w};
        #pragma unroll
        for (int e = 0; e < 8; e += 2) {
            acc0a = fmaf(s[e],     w0[e],     acc0a);
            acc1a = fmaf(s[e],     w1[e],     acc1a);
            acc2a = fmaf(s[e],     w2[e],     acc2a);
            acc0b = fmaf(s[e + 1], w0[e + 1], acc0b);
            acc1b = fmaf(s[e + 1], w1[e + 1], acc1b);
            acc2b = fmaf(s[e + 1], w2[e + 1], acc2b);
        }
    }

    const float o0 = fmaf(NEG_HALF_LN2, acc0a + acc0b, b2[0]);
    const float o1 = fmaf(NEG_HALF_LN2, acc1a + acc1b, b2[1]);
    const float o2 = fmaf(NEG_HALF_LN2, acc2a + acc2b, b2[2]);
    const int i = I * 16 + ti, j = J * 16 + tj;
    float* p1 = out + ((size_t)(b * N_ + i) * N_ + j) * C_;
    float* p2 = out + ((size_t)(b * N_ + j) * N_ + i) * C_;
    p1[0] = o0; p1[1] = o1; p1[2] = o2;
    p2[0] = o0; p2[1] = o1; p2[2] = o2;   // diagonal tiles: identical duplicate, benign
}

extern "C" void kernel_launch(void* const* d_in, const int* in_sizes, int n_in,
                              void* d_out, int out_size, void* d_ws, size_t ws_size,
                              hipStream_t stream) {
    const float* hd = (const float*)d_in[0];
    const float* W1 = (const float*)d_in[1];
    const float* b1 = (const float*)d_in[2];
    const float* W2 = (const float*)d_in[3];
    const float* b2 = (const float*)d_in[4];
    float* out = (float*)d_out;

    _Float16* At = (_Float16*)d_ws;          // [B*N][H] f16 = 512 KiB (scaled by -log2e)
    _Float16* Bt = At + B_ * N_ * H_;        // [B*N][H] f16 = 512 KiB

    proj_gemm<<<dim3((B_ * N_) / 32, 4), dim3(256), 0, stream>>>(hd, W1, b1, At, Bt);

    const int T = N_ / 16;                   // 32 -> 528 upper-tri tile pairs
    pair_kernel<<<dim3(T * (T + 1) / 2, B_), dim3(256), 0, stream>>>(At, Bt, W2, b2, out);
}

// Round 9
// 39.251 us; speedup vs baseline: 1.5834x; 1.1015x over previous
//
#include <hip/hip_runtime.h>
#include <hip/hip_fp16.h>

// Problem constants (reference: B,N,D,H,C = 4,512,128,128,3)
#define B_ 4
#define N_ 512
#define D_ 128
#define H_ 128
#define C_ 3

#define NEG_LOG2E   (-1.4426950408889634f)
#define NEG_HALF_LN2 (-0.34657359027997264f)   // -0.5 * ln(2)

typedef _Float16 half8  __attribute__((ext_vector_type(8)));
typedef _Float16 half4v __attribute__((ext_vector_type(4)));

__device__ __forceinline__ float exp2_fast(float x) {
    return __builtin_amdgcn_exp2f(x);   // raw v_exp_f32 (2^x)
}

// Projections stored PRE-SCALED by -log2e, in f16:
//   At[row][h] = f16(-log2e * (dot(h[row], W1[h][0:128]) + b1[h]))
//   Bt[row][h] = f16(-log2e *  dot(h[row], W1[h][128:256]))
__global__ __launch_bounds__(256) void proj_gemm(
    const float* __restrict__ hd, const float* __restrict__ W1,
    const float* __restrict__ b1, _Float16* __restrict__ At, _Float16* __restrict__ Bt)
{
    __shared__ float hsT[64][36];   // [k][m]
    __shared__ float wt [64][68];   // [k][o]
    const int m0      = blockIdx.x * 32;
    const int by      = blockIdx.y;        // 0..3
    const int halfSel = by >> 1;           // 0 -> At, 1 -> Bt
    const int wrow0   = (by & 1) * 64;     // W1 row base (== output h-col base)

    const int t  = threadIdx.x;
    const int r  = t >> 4, c4 = t & 15;
    const int tx = t & 15, ty = t >> 4;

    float acc[2][4] = {};

    for (int kc = 0; kc < 2; ++kc) {
        if (kc) __syncthreads();
        #pragma unroll
        for (int i = 0; i < 2; ++i) {
            const int m = r + 16 * i;
            float4 v = *(const float4*)&hd[(m0 + m) * D_ + kc * 64 + 4 * c4];
            hsT[4 * c4 + 0][m] = v.x; hsT[4 * c4 + 1][m] = v.y;
            hsT[4 * c4 + 2][m] = v.z; hsT[4 * c4 + 3][m] = v.w;
        }
        #pragma unroll
        for (int i = 0; i < 4; ++i) {
            const int o = r + 16 * i;
            float4 v = *(const float4*)&W1[(wrow0 + o) * (2 * D_) + halfSel * D_ + kc * 64 + 4 * c4];
            wt[4 * c4 + 0][o] = v.x; wt[4 * c4 + 1][o] = v.y;
            wt[4 * c4 + 2][o] = v.z; wt[4 * c4 + 3][o] = v.w;
        }
        __syncthreads();
        #pragma unroll 8
        for (int k = 0; k < 64; ++k) {
            float2 a  = *(const float2*)&hsT[k][2 * ty];
            float4 bv = *(const float4*)&wt [k][4 * tx];
            acc[0][0] = fmaf(a.x, bv.x, acc[0][0]); acc[0][1] = fmaf(a.x, bv.y, acc[0][1]);
            acc[0][2] = fmaf(a.x, bv.z, acc[0][2]); acc[0][3] = fmaf(a.x, bv.w, acc[0][3]);
            acc[1][0] = fmaf(a.y, bv.x, acc[1][0]); acc[1][1] = fmaf(a.y, bv.y, acc[1][1]);
            acc[1][2] = fmaf(a.y, bv.z, acc[1][2]); acc[1][3] = fmaf(a.y, bv.w, acc[1][3]);
        }
    }

    _Float16* dst = halfSel ? Bt : At;
    const int ocol = wrow0 + 4 * tx;
    float4 bias = make_float4(0.f, 0.f, 0.f, 0.f);
    if (!halfSel) bias = *(const float4*)&b1[ocol];
    #pragma unroll
    for (int i = 0; i < 2; ++i) {
        half4v o;
        o[0] = (_Float16)((acc[i][0] + bias.x) * NEG_LOG2E);
        o[1] = (_Float16)((acc[i][1] + bias.y) * NEG_LOG2E);
        o[2] = (_Float16)((acc[i][2] + bias.z) * NEG_LOG2E);
        o[3] = (_Float16)((acc[i][3] + bias.w) * NEG_LOG2E);
        *(half4v*)&dst[(m0 + 2 * ty + i) * H_ + ocol] = o;
    }
}

// One block per (batch, upper-tri 16x16 tile pair). EXP-FACTORIZATION:
// e^(y_i + y_j) = E_i * E_j, so exps are computed once per ROW at staging
// (4K exps/block) instead of per PAIR in the inner loop (65K). Inner loop
// per (pair,h), all packed f16 up to the final f32 rcp:
//   y1 = yAI+yBJ, y2 = yAJ+yBI          (pk_add)
//   e1 = eAI*eBJ, e2 = eAJ*eBI          (pk_mul)
//   d  = 1+e; p = d1*d2; num = y1*d2+y2*d1   (pk)
//   s  = f32(num) * rcp_f32(f32(p))     (1 trans/h)
//   acc_c += s * W2[c][h]
// LDS: 8 tiles [16][64] f16 = 16 KB, chunk-XOR swizzle (no pad), h split
// into 2 phases with restaging.
__global__ __launch_bounds__(256, 4) void pair_kernel(
    const _Float16* __restrict__ At, const _Float16* __restrict__ Bt,
    const float* __restrict__ W2, const float* __restrict__ b2,
    float* __restrict__ out)
{
    __shared__ _Float16 tiles[8][16 * 64];   // 0-3: yAI,yAJ,yBI,yBJ; 4-7: eAI,eAJ,eBI,eBJ
    const int T = N_ / 16;  // 32 tiles per dim
    int tp = blockIdx.x;
    const int b = blockIdx.y;
    int I = 0;
    while (tp >= T - I) { tp -= T - I; ++I; }   // uniform scalar decode
    const int J = I + tp;

    const int tid = threadIdx.x;
    // staging role: wave w stages tile w (AI/AJ/BI/BJ); 16 rows x 4 chunk-slots
    const int stile = tid >> 6;            // wave-uniform
    const int srow  = (tid >> 2) & 15;
    const int scc   = tid & 3;
    const _Float16* gsrc = ((stile & 2) ? Bt : At)
        + (size_t)(b * N_ + ((stile & 1) ? J : I) * 16 + srow) * H_;
    _Float16* ybase = &tiles[stile][srow * 64];
    _Float16* ebase = &tiles[stile + 4][srow * 64];
    const int sxor = srow & 7;

    const int ti = tid >> 4, tj = tid & 15;
    const int xI = ti & 7, xJ = tj & 7;

    float acc0a = 0.f, acc1a = 0.f, acc2a = 0.f;
    float acc0b = 0.f, acc1b = 0.f, acc2b = 0.f;

    for (int ph = 0; ph < 2; ++ph) {
        if (ph) __syncthreads();   // all reads of previous phase done before overwrite
        #pragma unroll
        for (int q = 0; q < 2; ++q) {
            const int c = scc + 4 * q;     // chunk 0..7 (8 f16 each)
            half8 yv = *(const half8*)&gsrc[ph * 64 + c * 8];
            half8 ev;
            #pragma unroll
            for (int e = 0; e < 8; ++e)
                ev[e] = (_Float16)exp2_fast((float)yv[e]);
            const int cs = (c ^ sxor) * 8;  // swizzled chunk slot
            *(half8*)&ybase[cs] = yv;
            *(half8*)&ebase[cs] = ev;
        }
        __syncthreads();

        #pragma unroll 2
        for (int c = 0; c < 8; ++c) {
            const int oI = ti * 64 + ((c ^ xI) * 8);
            const int oJ = tj * 64 + ((c ^ xJ) * 8);
            half8 yAI = *(const half8*)&tiles[0][oI];
            half8 yAJ = *(const half8*)&tiles[1][oJ];
            half8 yBI = *(const half8*)&tiles[2][oI];
            half8 yBJ = *(const half8*)&tiles[3][oJ];
            half8 eAI = *(const half8*)&tiles[4][oI];
            half8 eAJ = *(const half8*)&tiles[5][oJ];
            half8 eBI = *(const half8*)&tiles[6][oI];
            half8 eBJ = *(const half8*)&tiles[7][oJ];

            half8 y1 = yAI + yBJ;                    // v_pk_add_f16
            half8 y2 = yAJ + yBI;
            half8 e1 = eAI * eBJ;                    // v_pk_mul_f16
            half8 e2 = eAJ * eBI;
            half8 d1 = e1 + (_Float16)1.0f;
            half8 d2 = e2 + (_Float16)1.0f;
            half8 pp = d1 * d2;
            half8 num = y1 * d2 + y2 * d1;           // pk_mul + pk_fma

            const int hb = ph * 64 + c * 8;
            float4 w0a = *(const float4*)&W2[hb],          w0b = *(const float4*)&W2[hb + 4];
            float4 w1a = *(const float4*)&W2[H_ + hb],     w1b = *(const float4*)&W2[H_ + hb + 4];
            float4 w2a = *(const float4*)&W2[2 * H_ + hb], w2b = *(const float4*)&W2[2 * H_ + hb + 4];
            const float w0[8] = {w0a.x, w0a.y, w0a.z, w0a.w, w0b.x, w0b.y, w0b.z, w0b.w};
            const float w1[8] = {w1a.x, w1a.y, w1a.z, w1a.w, w1b.x, w1b.y, w1b.z, w1b.w};
            const float w2[8] = {w2a.x, w2a.y, w2a.z, w2a.w, w2b.x, w2b.y, w2b.z, w2b.w};

            #pragma unroll
            for (int e = 0; e < 8; e += 2) {
                const float sa = (float)num[e]     * __builtin_amdgcn_rcpf((float)pp[e]);
                const float sb = (float)num[e + 1] * __builtin_amdgcn_rcpf((float)pp[e + 1]);
                acc0a = fmaf(sa, w0[e],     acc0a);
                acc1a = fmaf(sa, w1[e],     acc1a);
                acc2a = fmaf(sa, w2[e],     acc2a);
                acc0b = fmaf(sb, w0[e + 1], acc0b);
                acc1b = fmaf(sb, w1[e + 1], acc1b);
                acc2b = fmaf(sb, w2[e + 1], acc2b);
            }
        }
    }

    const float o0 = fmaf(NEG_HALF_LN2, acc0a + acc0b, b2[0]);
    const float o1 = fmaf(NEG_HALF_LN2, acc1a + acc1b, b2[1]);
    const float o2 = fmaf(NEG_HALF_LN2, acc2a + acc2b, b2[2]);
    const int i = I * 16 + ti, j = J * 16 + tj;
    float* p1 = out + ((size_t)(b * N_ + i) * N_ + j) * C_;
    float* p2 = out + ((size_t)(b * N_ + j) * N_ + i) * C_;
    p1[0] = o0; p1[1] = o1; p1[2] = o2;
    p2[0] = o0; p2[1] = o1; p2[2] = o2;   // diagonal tiles: identical duplicate, benign
}

extern "C" void kernel_launch(void* const* d_in, const int* in_sizes, int n_in,
                              void* d_out, int out_size, void* d_ws, size_t ws_size,
                              hipStream_t stream) {
    const float* hd = (const float*)d_in[0];
    const float* W1 = (const float*)d_in[1];
    const float* b1 = (const float*)d_in[2];
    const float* W2 = (const float*)d_in[3];
    const float* b2 = (const float*)d_in[4];
    float* out = (float*)d_out;

    _Float16* At = (_Float16*)d_ws;          // [B*N][H] f16 = 512 KiB (scaled by -log2e)
    _Float16* Bt = At + B_ * N_ * H_;        // [B*N][H] f16 = 512 KiB

    proj_gemm<<<dim3((B_ * N_) / 32, 4), dim3(256), 0, stream>>>(hd, W1, b1, At, Bt);

    const int T = N_ / 16;                   // 32 -> 528 upper-tri tile pairs
    pair_kernel<<<dim3(T * (T + 1) / 2, B_), dim3(256), 0, stream>>>(At, Bt, W2, b2, out);
}